// Round 1
// baseline (434.332 us; speedup 1.0000x reference)
//
#include <hip/hip_runtime.h>
#include <hip/hip_bf16.h>

#define N_NODES 8192
#define N_EDGES 131072
#define D_DIM   128
#define R_DIM   32
#define LN_EPS  1e-5f

__device__ __forceinline__ float silu_f(float x) {
    return x / (1.0f + __expf(-x));
}

__device__ __forceinline__ void fma4(float4& acc, float s, const float4& b) {
    acc.x = fmaf(s, b.x, acc.x);
    acc.y = fmaf(s, b.y, acc.y);
    acc.z = fmaf(s, b.z, acc.z);
    acc.w = fmaf(s, b.w, acc.w);
}

// ---------------------------------------------------------------------------
// Kernel 1: per-node projections.
//   eq[n,l,r] = sum_d X_ls[n,l,d] * W_vq[d,r]          (all 15 l)
//   ek[n,l,r] = sum_d X_deg(l)[n,l,d] * W_vk{deg}[d,r]
// One block per node (256 thr = 4 waves). Wave 0/1 -> eq (l 0..7 / 8..14),
// wave 2 -> ek l 0..7 (Wvk0,Wvk1), wave 3 -> ek l 8..14 (Wvk2).
// Lane split: dc = lane>>4 (4 chunks of 32 d), rg = lane&15 (pair of r).
// W cached in 32 float2 regs; shfl_xor reduce over dc.
// ---------------------------------------------------------------------------
__global__ __launch_bounds__(256) void proj_kernel(
    const float* __restrict__ X0, const float* __restrict__ X1,
    const float* __restrict__ X2,
    const float* __restrict__ Wvq, const float* __restrict__ Wvk0,
    const float* __restrict__ Wvk1, const float* __restrict__ Wvk2,
    float* __restrict__ eq, float* __restrict__ ek)
{
    __shared__ float Xlds[15 * 128];
    const int node = blockIdx.x;
    const int tid  = threadIdx.x;

    // stage X_ls[node] : 15 rows x 128 = 480 float4
    for (int f = tid; f < 480; f += 256) {
        int l  = f >> 5;          // 32 float4 per row
        int c4 = (f & 31) * 4;
        const float* src;
        if (l < 3)      src = X0 + (node * 3 + l)     * 128;
        else if (l < 8) src = X1 + (node * 5 + (l-3)) * 128;
        else            src = X2 + (node * 7 + (l-8)) * 128;
        *(float4*)&Xlds[l * 128 + c4] = *(const float4*)&src[c4];
    }
    __syncthreads();

    const int wave = tid >> 6;
    const int lane = tid & 63;
    const int dc   = lane >> 4;   // 0..3  -> d chunk of 32
    const int rg   = lane & 15;   // 0..15 -> r pair

    auto do_seg = [&](const float* __restrict__ W, int lbeg, int lend,
                      float* __restrict__ outp) {
        float2 w[32];
        #pragma unroll
        for (int i = 0; i < 32; ++i)
            w[i] = *(const float2*)&W[(dc * 32 + i) * R_DIM + rg * 2];
        for (int l = lbeg; l < lend; ++l) {
            float ax = 0.f, ay = 0.f;
            #pragma unroll
            for (int j = 0; j < 8; ++j) {
                float4 x = *(const float4*)&Xlds[l * 128 + dc * 32 + j * 4];
                ax = fmaf(x.x, w[j*4+0].x, ax); ay = fmaf(x.x, w[j*4+0].y, ay);
                ax = fmaf(x.y, w[j*4+1].x, ax); ay = fmaf(x.y, w[j*4+1].y, ay);
                ax = fmaf(x.z, w[j*4+2].x, ax); ay = fmaf(x.z, w[j*4+2].y, ay);
                ax = fmaf(x.w, w[j*4+3].x, ax); ay = fmaf(x.w, w[j*4+3].y, ay);
            }
            ax += __shfl_xor(ax, 16); ay += __shfl_xor(ay, 16);
            ax += __shfl_xor(ax, 32); ay += __shfl_xor(ay, 32);
            if (dc == 0) {
                float2 o; o.x = ax; o.y = ay;
                *(float2*)&outp[node * 480 + l * 32 + rg * 2] = o;
            }
        }
    };

    if (wave == 0)      do_seg(Wvq, 0, 8,  eq);
    else if (wave == 1) do_seg(Wvq, 8, 15, eq);
    else if (wave == 2) { do_seg(Wvk0, 0, 3, ek); do_seg(Wvk1, 3, 8, ek); }
    else                do_seg(Wvk2, 8, 15, ek);
}

// ---------------------------------------------------------------------------
// Kernel 2: fused per-edge pipeline, 64 edges per block, 256 threads.
//   Phase A: gather eq[n_i], ek[n_j], per-degree rejection, w=sum q*k,
//            LayerNorm over R=32 (half-wave shuffle) -> wn_tile LDS.
//   Phase B: dw = wn @ W_w + b_w           (kept in regs)
//   Phase C: h  = silu(t_ij @ W_t1 + b_t1) (h written back to Atile)
//   Phase D: t  = h @ W_t2 + b_t2 ; out = dw * silu(t)
// GEMM thread tile: 8 edges x 4 cols (eg = tid>>5, cg = tid&31).
// ---------------------------------------------------------------------------
__global__ __launch_bounds__(256) void edge_kernel(
    const float* __restrict__ eq, const float* __restrict__ ek,
    const float* __restrict__ t_ij,
    const float* __restrict__ r0, const float* __restrict__ r1,
    const float* __restrict__ r2,
    const int* __restrict__ eidx,
    const float* __restrict__ ln_g, const float* __restrict__ ln_b,
    const float* __restrict__ W_w,  const float* __restrict__ b_w,
    const float* __restrict__ W_t1, const float* __restrict__ b_t1,
    const float* __restrict__ W_t2, const float* __restrict__ b_t2,
    float* __restrict__ out)
{
    __shared__ float Atile[64][132];    // t_ij tile, then h tile
    __shared__ float Btile[32][132];    // W_w, then W_t1/W_t2 k-chunks
    __shared__ float wn_tile[64][36];

    const int tid  = threadIdx.x;
    const int tile = blockIdx.x * 64;

    // stage t_ij tile (Atile) and W_w (Btile) up front
    #pragma unroll
    for (int i = 0; i < 8; ++i) {
        int f = tid + i * 256;          // 2048 float4
        int row = f >> 5, c4 = (f & 31) * 4;
        *(float4*)&Atile[row][c4] =
            *(const float4*)&t_ij[(tile + row) * 128 + c4];
    }
    #pragma unroll
    for (int i = 0; i < 4; ++i) {
        int f = tid + i * 256;          // 1024 float4
        int row = f >> 5, c4 = (f & 31) * 4;
        *(float4*)&Btile[row][c4] = *(const float4*)&W_w[row * 128 + c4];
    }

    // ---- Phase A: wn for 64 edges, half-wave (32 lanes = r) per edge ----
    {
        const int hw = tid >> 5;        // 0..7 half-wave id
        const int r  = tid & 31;
        const float g  = ln_g[r];
        const float bb = ln_b[r];
        #pragma unroll 1
        for (int it = 0; it < 8; ++it) {
            const int le = hw * 8 + it;
            const int e  = tile + le;
            const int nj = eidx[e];              // edge_index[0] = n_j
            const int ni = eidx[N_EDGES + e];    // edge_index[1] = n_i
            float q[15], k[15], rv[15];
            const float* qp = eq + ni * 480 + r;
            const float* kp = ek + nj * 480 + r;
            #pragma unroll
            for (int l = 0; l < 15; ++l) { q[l] = qp[l * 32]; k[l] = kp[l * 32]; }
            #pragma unroll
            for (int c = 0; c < 3; ++c) rv[c]     = r0[e * 3 + c];
            #pragma unroll
            for (int c = 0; c < 5; ++c) rv[3 + c] = r1[e * 5 + c];
            #pragma unroll
            for (int c = 0; c < 7; ++c) rv[8 + c] = r2[e * 7 + c];
            // per-degree vector rejection (note: rej(x,-r) == rej(x,r))
            float dq, dk;
            dq = q[0]*rv[0] + q[1]*rv[1] + q[2]*rv[2];
            dk = k[0]*rv[0] + k[1]*rv[1] + k[2]*rv[2];
            #pragma unroll
            for (int l = 0; l < 3; ++l) { q[l] -= dq * rv[l]; k[l] -= dk * rv[l]; }
            dq = 0.f; dk = 0.f;
            #pragma unroll
            for (int l = 3; l < 8; ++l) { dq += q[l]*rv[l]; dk += k[l]*rv[l]; }
            #pragma unroll
            for (int l = 3; l < 8; ++l) { q[l] -= dq * rv[l]; k[l] -= dk * rv[l]; }
            dq = 0.f; dk = 0.f;
            #pragma unroll
            for (int l = 8; l < 15; ++l) { dq += q[l]*rv[l]; dk += k[l]*rv[l]; }
            #pragma unroll
            for (int l = 8; l < 15; ++l) { q[l] -= dq * rv[l]; k[l] -= dk * rv[l]; }
            float w = 0.f;
            #pragma unroll
            for (int l = 0; l < 15; ++l) w = fmaf(q[l], k[l], w);
            // LayerNorm over the 32 lanes of this half-wave
            float s = w, s2 = w * w;
            s += __shfl_xor(s, 1);  s2 += __shfl_xor(s2, 1);
            s += __shfl_xor(s, 2);  s2 += __shfl_xor(s2, 2);
            s += __shfl_xor(s, 4);  s2 += __shfl_xor(s2, 4);
            s += __shfl_xor(s, 8);  s2 += __shfl_xor(s2, 8);
            s += __shfl_xor(s, 16); s2 += __shfl_xor(s2, 16);
            const float mu  = s * (1.f / 32.f);
            const float var = s2 * (1.f / 32.f) - mu * mu;
            const float wn  = (w - mu) * rsqrtf(var + LN_EPS) * g + bb;
            wn_tile[le][r] = wn;
        }
    }
    __syncthreads();

    const int eg  = tid >> 5;      // 8 edge groups x 8 edges
    const int cg  = tid & 31;      // 32 col groups x 4 cols
    const int le0 = eg * 8;

    // ---- Phase B: dw = wn @ W_w + b_w ----
    float4 dwacc[8];
    #pragma unroll
    for (int e = 0; e < 8; ++e) { dwacc[e].x = dwacc[e].y = dwacc[e].z = dwacc[e].w = 0.f; }
    #pragma unroll
    for (int k4 = 0; k4 < 8; ++k4) {
        float4 b0 = *(const float4*)&Btile[k4*4+0][cg*4];
        float4 b1 = *(const float4*)&Btile[k4*4+1][cg*4];
        float4 b2 = *(const float4*)&Btile[k4*4+2][cg*4];
        float4 b3 = *(const float4*)&Btile[k4*4+3][cg*4];
        #pragma unroll
        for (int e = 0; e < 8; ++e) {
            float4 a = *(const float4*)&wn_tile[le0+e][k4*4];
            fma4(dwacc[e], a.x, b0);
            fma4(dwacc[e], a.y, b1);
            fma4(dwacc[e], a.z, b2);
            fma4(dwacc[e], a.w, b3);
        }
    }
    {
        float4 bw = *(const float4*)&b_w[cg*4];
        #pragma unroll
        for (int e = 0; e < 8; ++e) {
            dwacc[e].x += bw.x; dwacc[e].y += bw.y;
            dwacc[e].z += bw.z; dwacc[e].w += bw.w;
        }
    }

    // ---- Phase C: h = silu(t @ W_t1 + b_t1) ----
    float4 tacc[8];
    #pragma unroll
    for (int e = 0; e < 8; ++e) { tacc[e].x = tacc[e].y = tacc[e].z = tacc[e].w = 0.f; }
    for (int ch = 0; ch < 4; ++ch) {
        __syncthreads();   // previous Btile consumers done
        #pragma unroll
        for (int i = 0; i < 4; ++i) {
            int f = tid + i * 256;
            int row = f >> 5, c4 = (f & 31) * 4;
            *(float4*)&Btile[row][c4] =
                *(const float4*)&W_t1[(ch * 32 + row) * 128 + c4];
        }
        __syncthreads();
        #pragma unroll
        for (int k4 = 0; k4 < 8; ++k4) {
            float4 b0 = *(const float4*)&Btile[k4*4+0][cg*4];
            float4 b1 = *(const float4*)&Btile[k4*4+1][cg*4];
            float4 b2 = *(const float4*)&Btile[k4*4+2][cg*4];
            float4 b3 = *(const float4*)&Btile[k4*4+3][cg*4];
            #pragma unroll
            for (int e = 0; e < 8; ++e) {
                float4 a = *(const float4*)&Atile[le0+e][ch*32 + k4*4];
                fma4(tacc[e], a.x, b0);
                fma4(tacc[e], a.y, b1);
                fma4(tacc[e], a.z, b2);
                fma4(tacc[e], a.w, b3);
            }
        }
    }
    __syncthreads();   // all Atile (t_ij) reads complete
    {
        float4 bt1 = *(const float4*)&b_t1[cg*4];
        #pragma unroll
        for (int e = 0; e < 8; ++e) {
            float4 h;
            h.x = silu_f(tacc[e].x + bt1.x);
            h.y = silu_f(tacc[e].y + bt1.y);
            h.z = silu_f(tacc[e].z + bt1.z);
            h.w = silu_f(tacc[e].w + bt1.w);
            *(float4*)&Atile[le0+e][cg*4] = h;
        }
    }
    __syncthreads();

    // ---- Phase D: t = h @ W_t2 + b_t2 ; out = dw * silu(t) ----
    float4 oacc[8];
    #pragma unroll
    for (int e = 0; e < 8; ++e) { oacc[e].x = oacc[e].y = oacc[e].z = oacc[e].w = 0.f; }
    for (int ch = 0; ch < 4; ++ch) {
        __syncthreads();
        #pragma unroll
        for (int i = 0; i < 4; ++i) {
            int f = tid + i * 256;
            int row = f >> 5, c4 = (f & 31) * 4;
            *(float4*)&Btile[row][c4] =
                *(const float4*)&W_t2[(ch * 32 + row) * 128 + c4];
        }
        __syncthreads();
        #pragma unroll
        for (int k4 = 0; k4 < 8; ++k4) {
            float4 b0 = *(const float4*)&Btile[k4*4+0][cg*4];
            float4 b1 = *(const float4*)&Btile[k4*4+1][cg*4];
            float4 b2 = *(const float4*)&Btile[k4*4+2][cg*4];
            float4 b3 = *(const float4*)&Btile[k4*4+3][cg*4];
            #pragma unroll
            for (int e = 0; e < 8; ++e) {
                float4 a = *(const float4*)&Atile[le0+e][ch*32 + k4*4];
                fma4(oacc[e], a.x, b0);
                fma4(oacc[e], a.y, b1);
                fma4(oacc[e], a.z, b2);
                fma4(oacc[e], a.w, b3);
            }
        }
    }
    {
        float4 bt2 = *(const float4*)&b_t2[cg*4];
        #pragma unroll
        for (int e = 0; e < 8; ++e) {
            float4 tv, o;
            tv.x = silu_f(oacc[e].x + bt2.x);
            tv.y = silu_f(oacc[e].y + bt2.y);
            tv.z = silu_f(oacc[e].z + bt2.z);
            tv.w = silu_f(oacc[e].w + bt2.w);
            o.x = dwacc[e].x * tv.x;
            o.y = dwacc[e].y * tv.y;
            o.z = dwacc[e].z * tv.z;
            o.w = dwacc[e].w * tv.w;
            *(float4*)&out[(tile + le0 + e) * 128 + cg * 4] = o;
        }
    }
}

extern "C" void kernel_launch(void* const* d_in, const int* in_sizes, int n_in,
                              void* d_out, int out_size, void* d_ws, size_t ws_size,
                              hipStream_t stream) {
    (void)in_sizes; (void)n_in; (void)out_size; (void)ws_size;
    const float* X0   = (const float*)d_in[0];
    const float* X1   = (const float*)d_in[1];
    const float* X2   = (const float*)d_in[2];
    const float* t_ij = (const float*)d_in[3];
    const float* r0   = (const float*)d_in[4];
    const float* r1   = (const float*)d_in[5];
    const float* r2   = (const float*)d_in[6];
    const int*   eidx = (const int*)d_in[7];
    const float* Wvq  = (const float*)d_in[8];
    const float* Wvk0 = (const float*)d_in[9];
    const float* Wvk1 = (const float*)d_in[10];
    const float* Wvk2 = (const float*)d_in[11];
    const float* ln_g = (const float*)d_in[12];
    const float* ln_b = (const float*)d_in[13];
    const float* W_w  = (const float*)d_in[14];
    const float* b_w  = (const float*)d_in[15];
    const float* W_t1 = (const float*)d_in[16];
    const float* b_t1 = (const float*)d_in[17];
    const float* W_t2 = (const float*)d_in[18];
    const float* b_t2 = (const float*)d_in[19];
    float* out = (float*)d_out;

    float* eq = (float*)d_ws;                 // [N, 15, 32]
    float* ek = eq + (size_t)N_NODES * 480;   // [N, 15, 32]

    proj_kernel<<<N_NODES, 256, 0, stream>>>(X0, X1, X2, Wvq, Wvk0, Wvk1, Wvk2,
                                             eq, ek);
    edge_kernel<<<N_EDGES / 64, 256, 0, stream>>>(eq, ek, t_ij, r0, r1, r2, eidx,
                                                  ln_g, ln_b, W_w, b_w,
                                                  W_t1, b_t1, W_t2, b_t2, out);
}

// Round 2
// 161.666 us; speedup vs baseline: 2.6866x; 2.6866x over previous
//
#include <hip/hip_runtime.h>
#include <hip/hip_bf16.h>

#define N_NODES 8192
#define N_EDGES 131072
#define LN_EPS  1e-5f

typedef __attribute__((ext_vector_type(8))) short bf16x8;
typedef __attribute__((ext_vector_type(4))) float f32x4;

__device__ __forceinline__ float silu_f(float x) {
    return x / (1.0f + __expf(-x));
}

// round-to-nearest-even fp32 -> bf16
__device__ __forceinline__ unsigned short f2bf(float x) {
    union { float f; unsigned int u; } v; v.f = x;
    unsigned int r = v.u + 0x7FFFu + ((v.u >> 16) & 1u);
    return (unsigned short)(r >> 16);
}
__device__ __forceinline__ unsigned int pk2(float a, float b) {
    return (unsigned int)f2bf(a) | ((unsigned int)f2bf(b) << 16);
}
__device__ __forceinline__ f32x4 mfma16(bf16x8 a, bf16x8 b, f32x4 c) {
    return __builtin_amdgcn_mfma_f32_16x16x32_bf16(a, b, c, 0, 0, 0);
}

// ---------------------------------------------------------------------------
// Kernel 0: weight prep — transpose W_w/W_t1/W_t2 to bf16 [n][k] (k contiguous)
// ---------------------------------------------------------------------------
__global__ __launch_bounds__(256) void prep_kernel(
    const float* __restrict__ W_w, const float* __restrict__ W_t1,
    const float* __restrict__ W_t2,
    unsigned short* __restrict__ Wtw, unsigned short* __restrict__ Wt1,
    unsigned short* __restrict__ Wt2)
{
    int i = blockIdx.x * 256 + threadIdx.x;
    if (i < 16384) {
        int n = i >> 7, k = i & 127;
        Wt1[i] = f2bf(W_t1[k * 128 + n]);
        Wt2[i] = f2bf(W_t2[k * 128 + n]);
    }
    if (i < 4096) {
        int n = i >> 5, k = i & 31;
        Wtw[i] = f2bf(W_w[k * 128 + n]);
    }
}

// ---------------------------------------------------------------------------
// Kernel 1: per-node projections (unchanged from round 1 — verified).
// ---------------------------------------------------------------------------
__global__ __launch_bounds__(256) void proj_kernel(
    const float* __restrict__ X0, const float* __restrict__ X1,
    const float* __restrict__ X2,
    const float* __restrict__ Wvq, const float* __restrict__ Wvk0,
    const float* __restrict__ Wvk1, const float* __restrict__ Wvk2,
    float* __restrict__ eq, float* __restrict__ ek)
{
    __shared__ float Xlds[15 * 128];
    const int node = blockIdx.x;
    const int tid  = threadIdx.x;

    for (int f = tid; f < 480; f += 256) {
        int l  = f >> 5;
        int c4 = (f & 31) * 4;
        const float* src;
        if (l < 3)      src = X0 + (node * 3 + l)     * 128;
        else if (l < 8) src = X1 + (node * 5 + (l-3)) * 128;
        else            src = X2 + (node * 7 + (l-8)) * 128;
        *(float4*)&Xlds[l * 128 + c4] = *(const float4*)&src[c4];
    }
    __syncthreads();

    const int wave = tid >> 6;
    const int lane = tid & 63;
    const int dc   = lane >> 4;
    const int rg   = lane & 15;

    auto do_seg = [&](const float* __restrict__ W, int lbeg, int lend,
                      float* __restrict__ outp) {
        float2 w[32];
        #pragma unroll
        for (int i = 0; i < 32; ++i)
            w[i] = *(const float2*)&W[(dc * 32 + i) * 32 + rg * 2];
        for (int l = lbeg; l < lend; ++l) {
            float ax = 0.f, ay = 0.f;
            #pragma unroll
            for (int j = 0; j < 8; ++j) {
                float4 x = *(const float4*)&Xlds[l * 128 + dc * 32 + j * 4];
                ax = fmaf(x.x, w[j*4+0].x, ax); ay = fmaf(x.x, w[j*4+0].y, ay);
                ax = fmaf(x.y, w[j*4+1].x, ax); ay = fmaf(x.y, w[j*4+1].y, ay);
                ax = fmaf(x.z, w[j*4+2].x, ax); ay = fmaf(x.z, w[j*4+2].y, ay);
                ax = fmaf(x.w, w[j*4+3].x, ax); ay = fmaf(x.w, w[j*4+3].y, ay);
            }
            ax += __shfl_xor(ax, 16); ay += __shfl_xor(ay, 16);
            ax += __shfl_xor(ax, 32); ay += __shfl_xor(ay, 32);
            if (dc == 0) {
                float2 o; o.x = ax; o.y = ay;
                *(float2*)&outp[node * 480 + l * 32 + rg * 2] = o;
            }
        }
    };

    if (wave == 0)      do_seg(Wvq, 0, 8,  eq);
    else if (wave == 1) do_seg(Wvq, 8, 15, eq);
    else if (wave == 2) { do_seg(Wvk0, 0, 3, ek); do_seg(Wvk1, 3, 8, ek); }
    else                do_seg(Wvk2, 8, 15, ek);
}

// ---------------------------------------------------------------------------
// Kernel 2: fused per-edge pipeline with MFMA GEMMs.
// ---------------------------------------------------------------------------
__global__ __launch_bounds__(256) void edge_kernel(
    const float* __restrict__ eq, const float* __restrict__ ek,
    const float* __restrict__ t_ij,
    const float* __restrict__ r0, const float* __restrict__ r1,
    const float* __restrict__ r2,
    const int* __restrict__ eidx,
    const float* __restrict__ ln_g, const float* __restrict__ ln_b,
    const unsigned short* __restrict__ Wtw, const float* __restrict__ b_w,
    const unsigned short* __restrict__ Wt1, const float* __restrict__ b_t1,
    const unsigned short* __restrict__ Wt2, const float* __restrict__ b_t2,
    float* __restrict__ out)
{
    __shared__ __align__(16) unsigned short At[64 * 128];  // t_ij tile (bf16, swizzled)
    __shared__ __align__(16) unsigned short Ht[64 * 128];  // h tile
    __shared__ __align__(16) unsigned short Wn[64 * 32];   // wn tile

    const int tid  = threadIdx.x;
    const int tile = blockIdx.x * 64;

    // ---- stage t_ij tile -> bf16 swizzled At ----
    #pragma unroll
    for (int i = 0; i < 4; ++i) {
        int c   = tid + i * 256;          // 1024 chunks of 8 floats
        int row = c >> 4;
        int ke  = (c & 15) * 8;
        const float* src = &t_ij[(size_t)(tile + row) * 128 + ke];
        float4 a0 = *(const float4*)src;
        float4 a1 = *(const float4*)(src + 4);
        uint4 p;
        p.x = pk2(a0.x, a0.y); p.y = pk2(a0.z, a0.w);
        p.z = pk2(a1.x, a1.y); p.w = pk2(a1.z, a1.w);
        *(uint4*)((char*)At + ((row * 256 + ke * 2) ^ ((row & 7) << 4))) = p;
    }

    // ---- Phase A: wn for 64 edges (half-wave = 32 r-lanes per edge) ----
    {
        const int hw = tid >> 5;
        const int r  = tid & 31;
        const float g  = ln_g[r];
        const float bb = ln_b[r];
        #pragma unroll 1
        for (int it = 0; it < 8; ++it) {
            const int le = hw * 8 + it;
            const int e  = tile + le;
            const int nj = eidx[e];
            const int ni = eidx[N_EDGES + e];
            float q[15], k[15], rv[15];
            const float* qp = eq + ni * 480 + r;
            const float* kp = ek + nj * 480 + r;
            #pragma unroll
            for (int l = 0; l < 15; ++l) { q[l] = qp[l * 32]; k[l] = kp[l * 32]; }
            #pragma unroll
            for (int c = 0; c < 3; ++c) rv[c]     = r0[e * 3 + c];
            #pragma unroll
            for (int c = 0; c < 5; ++c) rv[3 + c] = r1[e * 5 + c];
            #pragma unroll
            for (int c = 0; c < 7; ++c) rv[8 + c] = r2[e * 7 + c];
            float dq, dk;
            dq = q[0]*rv[0] + q[1]*rv[1] + q[2]*rv[2];
            dk = k[0]*rv[0] + k[1]*rv[1] + k[2]*rv[2];
            #pragma unroll
            for (int l = 0; l < 3; ++l) { q[l] -= dq * rv[l]; k[l] -= dk * rv[l]; }
            dq = 0.f; dk = 0.f;
            #pragma unroll
            for (int l = 3; l < 8; ++l) { dq += q[l]*rv[l]; dk += k[l]*rv[l]; }
            #pragma unroll
            for (int l = 3; l < 8; ++l) { q[l] -= dq * rv[l]; k[l] -= dk * rv[l]; }
            dq = 0.f; dk = 0.f;
            #pragma unroll
            for (int l = 8; l < 15; ++l) { dq += q[l]*rv[l]; dk += k[l]*rv[l]; }
            #pragma unroll
            for (int l = 8; l < 15; ++l) { q[l] -= dq * rv[l]; k[l] -= dk * rv[l]; }
            float w = 0.f;
            #pragma unroll
            for (int l = 0; l < 15; ++l) w = fmaf(q[l], k[l], w);
            float s = w, s2 = w * w;
            s += __shfl_xor(s, 1);  s2 += __shfl_xor(s2, 1);
            s += __shfl_xor(s, 2);  s2 += __shfl_xor(s2, 2);
            s += __shfl_xor(s, 4);  s2 += __shfl_xor(s2, 4);
            s += __shfl_xor(s, 8);  s2 += __shfl_xor(s2, 8);
            s += __shfl_xor(s, 16); s2 += __shfl_xor(s2, 16);
            const float mu  = s * (1.f / 32.f);
            const float var = s2 * (1.f / 32.f) - mu * mu;
            const float wn  = (w - mu) * rsqrtf(var + LN_EPS) * g + bb;
            *(unsigned short*)((char*)Wn + ((le * 64 + r * 2) ^ ((le & 3) << 4)))
                = f2bf(wn);
        }
    }
    __syncthreads();

    const int lane = tid & 63;
    const int wv   = tid >> 6;
    const int wc   = wv * 32;          // wave's output col base
    const int l15  = lane & 15;
    const int lk   = lane >> 4;        // 0..3 (k-group)

    // ---- GEMM1: h = silu(t_ij @ W_t1 + b_t1) ----
    bf16x8 w1f[4][2];
    #pragma unroll
    for (int kt = 0; kt < 4; ++kt)
        #pragma unroll
        for (int ct = 0; ct < 2; ++ct)
            w1f[kt][ct] = *(const bf16x8*)
                &Wt1[(size_t)(wc + ct * 16 + l15) * 128 + kt * 32 + lk * 8];

    f32x4 tac[4][2];
    #pragma unroll
    for (int rt = 0; rt < 4; ++rt)
        #pragma unroll
        for (int ct = 0; ct < 2; ++ct)
            tac[rt][ct] = (f32x4){0.f, 0.f, 0.f, 0.f};

    #pragma unroll
    for (int kt = 0; kt < 4; ++kt) {
        #pragma unroll
        for (int rt = 0; rt < 4; ++rt) {
            int row = rt * 16 + l15;
            bf16x8 a = *(const bf16x8*)((const char*)At +
                ((row * 256 + kt * 64 + lk * 16) ^ ((row & 7) << 4)));
            tac[rt][0] = mfma16(a, w1f[kt][0], tac[rt][0]);
            tac[rt][1] = mfma16(a, w1f[kt][1], tac[rt][1]);
        }
    }

    {
        float bt1v0 = b_t1[wc + l15];
        float bt1v1 = b_t1[wc + 16 + l15];
        #pragma unroll
        for (int rt = 0; rt < 4; ++rt)
            #pragma unroll
            for (int ct = 0; ct < 2; ++ct) {
                float bb  = ct ? bt1v1 : bt1v0;
                int   col = wc + ct * 16 + l15;
                #pragma unroll
                for (int r = 0; r < 4; ++r) {
                    int row = rt * 16 + lk * 4 + r;
                    float hv = silu_f(tac[rt][ct][r] + bb);
                    *(unsigned short*)((char*)Ht +
                        ((row * 256 + col * 2) ^ ((row & 7) << 4))) = f2bf(hv);
                }
            }
    }
    __syncthreads();

    // ---- GEMM2: t = h @ W_t2 ----
    bf16x8 w2f[4][2];
    #pragma unroll
    for (int kt = 0; kt < 4; ++kt)
        #pragma unroll
        for (int ct = 0; ct < 2; ++ct)
            w2f[kt][ct] = *(const bf16x8*)
                &Wt2[(size_t)(wc + ct * 16 + l15) * 128 + kt * 32 + lk * 8];

    f32x4 oac[4][2];
    #pragma unroll
    for (int rt = 0; rt < 4; ++rt)
        #pragma unroll
        for (int ct = 0; ct < 2; ++ct)
            oac[rt][ct] = (f32x4){0.f, 0.f, 0.f, 0.f};

    #pragma unroll
    for (int kt = 0; kt < 4; ++kt) {
        #pragma unroll
        for (int rt = 0; rt < 4; ++rt) {
            int row = rt * 16 + l15;
            bf16x8 a = *(const bf16x8*)((const char*)Ht +
                ((row * 256 + kt * 64 + lk * 16) ^ ((row & 7) << 4)));
            oac[rt][0] = mfma16(a, w2f[kt][0], oac[rt][0]);
            oac[rt][1] = mfma16(a, w2f[kt][1], oac[rt][1]);
        }
    }

    // ---- dw GEMM: dw = wn @ W_w ----
    bf16x8 wwf[2];
    #pragma unroll
    for (int ct = 0; ct < 2; ++ct)
        wwf[ct] = *(const bf16x8*)&Wtw[(wc + ct * 16 + l15) * 32 + lk * 8];

    f32x4 dac[4][2];
    #pragma unroll
    for (int rt = 0; rt < 4; ++rt)
        #pragma unroll
        for (int ct = 0; ct < 2; ++ct)
            dac[rt][ct] = (f32x4){0.f, 0.f, 0.f, 0.f};

    #pragma unroll
    for (int rt = 0; rt < 4; ++rt) {
        int row = rt * 16 + l15;
        bf16x8 a = *(const bf16x8*)((const char*)Wn +
            ((row * 64 + lk * 16) ^ ((row & 3) << 4)));
        dac[rt][0] = mfma16(a, wwf[0], dac[rt][0]);
        dac[rt][1] = mfma16(a, wwf[1], dac[rt][1]);
    }

    // ---- Epilogue: out = (dw + b_w) * silu(t + b_t2) ----
    {
        float bw0 = b_w[wc + l15],  bw1 = b_w[wc + 16 + l15];
        float b20 = b_t2[wc + l15], b21 = b_t2[wc + 16 + l15];
        #pragma unroll
        for (int rt = 0; rt < 4; ++rt)
            #pragma unroll
            for (int ct = 0; ct < 2; ++ct) {
                float bwv = ct ? bw1 : bw0;
                float b2v = ct ? b21 : b20;
                int   col = wc + ct * 16 + l15;
                #pragma unroll
                for (int r = 0; r < 4; ++r) {
                    int row = rt * 16 + lk * 4 + r;
                    float dwv = dac[rt][ct][r] + bwv;
                    float tv  = silu_f(oac[rt][ct][r] + b2v);
                    out[(size_t)(tile + row) * 128 + col] = dwv * tv;
                }
            }
    }
}

extern "C" void kernel_launch(void* const* d_in, const int* in_sizes, int n_in,
                              void* d_out, int out_size, void* d_ws, size_t ws_size,
                              hipStream_t stream) {
    (void)in_sizes; (void)n_in; (void)out_size; (void)ws_size;
    const float* X0   = (const float*)d_in[0];
    const float* X1   = (const float*)d_in[1];
    const float* X2   = (const float*)d_in[2];
    const float* t_ij = (const float*)d_in[3];
    const float* r0   = (const float*)d_in[4];
    const float* r1   = (const float*)d_in[5];
    const float* r2   = (const float*)d_in[6];
    const int*   eidx = (const int*)d_in[7];
    const float* Wvq  = (const float*)d_in[8];
    const float* Wvk0 = (const float*)d_in[9];
    const float* Wvk1 = (const float*)d_in[10];
    const float* Wvk2 = (const float*)d_in[11];
    const float* ln_g = (const float*)d_in[12];
    const float* ln_b = (const float*)d_in[13];
    const float* W_w  = (const float*)d_in[14];
    const float* b_w  = (const float*)d_in[15];
    const float* W_t1 = (const float*)d_in[16];
    const float* b_t1 = (const float*)d_in[17];
    const float* W_t2 = (const float*)d_in[18];
    const float* b_t2 = (const float*)d_in[19];
    float* out = (float*)d_out;

    float* eq = (float*)d_ws;                         // [N,15,32] f32
    float* ek = eq + (size_t)N_NODES * 480;           // [N,15,32] f32
    unsigned short* Wtw = (unsigned short*)(ek + (size_t)N_NODES * 480);
    unsigned short* Wt1 = Wtw + 128 * 32;             // [128][128] bf16 (n-major)
    unsigned short* Wt2 = Wt1 + 128 * 128;

    prep_kernel<<<64, 256, 0, stream>>>(W_w, W_t1, W_t2, Wtw, Wt1, Wt2);
    proj_kernel<<<N_NODES, 256, 0, stream>>>(X0, X1, X2, Wvq, Wvk0, Wvk1, Wvk2,
                                             eq, ek);
    edge_kernel<<<N_EDGES / 64, 256, 0, stream>>>(eq, ek, t_ij, r0, r1, r2, eidx,
                                                  ln_g, ln_b, Wtw, b_w,
                                                  Wt1, b_t1, Wt2, b_t2, out);
}

// Round 3
// 112.960 us; speedup vs baseline: 3.8450x; 1.4312x over previous
//
#include <hip/hip_runtime.h>
#include <hip/hip_bf16.h>

#define N_NODES 8192
#define N_EDGES 131072
#define LN_EPS  1e-5f

typedef __attribute__((ext_vector_type(8))) short bf16x8;
typedef __attribute__((ext_vector_type(4))) float f32x4;

__device__ __forceinline__ float silu_f(float x) {
    return x / (1.0f + __expf(-x));
}

// round-to-nearest-even fp32 -> bf16
__device__ __forceinline__ unsigned short f2bf(float x) {
    union { float f; unsigned int u; } v; v.f = x;
    unsigned int r = v.u + 0x7FFFu + ((v.u >> 16) & 1u);
    return (unsigned short)(r >> 16);
}
__device__ __forceinline__ float bf2f(unsigned short u) {
    union { float f; unsigned int x; } v; v.x = ((unsigned int)u) << 16;
    return v.f;
}
__device__ __forceinline__ unsigned int pk2(float a, float b) {
    return (unsigned int)f2bf(a) | ((unsigned int)f2bf(b) << 16);
}
__device__ __forceinline__ f32x4 mfma16(bf16x8 a, bf16x8 b, f32x4 c) {
    return __builtin_amdgcn_mfma_f32_16x16x32_bf16(a, b, c, 0, 0, 0);
}

// ---------------------------------------------------------------------------
// Kernel 0: weight prep.
//   Wtw  [128][32]  = W_w^T  (n-major, k=r contiguous)   for dw GEMM B-operand
//   Wt1b [128][128] = W_t1^T                              for GEMM1 B-operand
//   Wt2b [128][128] = W_t2^T                              for GEMM2 B-operand
//   Wqt  [32][128]  = W_vq^T (r-major, k=d contiguous)    for proj A-operand
//   Wk0t/Wk1t/Wk2t  = W_vk*^T
// ---------------------------------------------------------------------------
__global__ __launch_bounds__(256) void prep_kernel(
    const float* __restrict__ W_w, const float* __restrict__ W_t1,
    const float* __restrict__ W_t2, const float* __restrict__ Wvq,
    const float* __restrict__ Wvk0, const float* __restrict__ Wvk1,
    const float* __restrict__ Wvk2,
    unsigned short* __restrict__ Wtw, unsigned short* __restrict__ Wt1b,
    unsigned short* __restrict__ Wt2b, unsigned short* __restrict__ Wqt,
    unsigned short* __restrict__ Wk0t, unsigned short* __restrict__ Wk1t,
    unsigned short* __restrict__ Wk2t)
{
    int i = blockIdx.x * 256 + threadIdx.x;
    if (i < 16384) {
        int n = i >> 7, k = i & 127;
        Wt1b[i] = f2bf(W_t1[k * 128 + n]);
        Wt2b[i] = f2bf(W_t2[k * 128 + n]);
    }
    if (i < 4096) {
        { int n = i >> 5, k = i & 31; Wtw[i] = f2bf(W_w[k * 128 + n]); }
        int r = i >> 7, d = i & 127;
        Wqt[i]  = f2bf(Wvq [d * 32 + r]);
        Wk0t[i] = f2bf(Wvk0[d * 32 + r]);
        Wk1t[i] = f2bf(Wvk1[d * 32 + r]);
        Wk2t[i] = f2bf(Wvk2[d * 32 + r]);
    }
}

// ---------------------------------------------------------------------------
// Kernel 1: MFMA projections. One degree-segment GEMM per block:
//   rows = flattened (n,l) of X_deg [N*S, 128]; cols = 32 r; K = 128.
// Swapped operands: mfma(A=W^T fragment, B=X fragment) -> D[r][xrow], so each
// lane stores 4 consecutive r (8B) per half. X tile staged once (bf16,
// XOR-swizzled), used for BOTH Wvq (-> eq) and Wvk_deg (-> ek).
// ---------------------------------------------------------------------------
template<int S, int LOFF>
__device__ __forceinline__ void proj_body(
    const float* __restrict__ X, const unsigned short* __restrict__ Wqt,
    const unsigned short* __restrict__ Wkt,
    unsigned short* __restrict__ eq, unsigned short* __restrict__ ek,
    int row0, unsigned short* Xl)
{
    const int tid = threadIdx.x;
    // stage 64 rows x 128 (f32 -> bf16, swizzled)
    #pragma unroll
    for (int i = 0; i < 4; ++i) {
        int c   = tid + i * 256;
        int row = c >> 4;
        int ke  = (c & 15) * 8;
        const float* src = &X[(size_t)(row0 + row) * 128 + ke];
        float4 a0 = *(const float4*)src;
        float4 a1 = *(const float4*)(src + 4);
        uint4 p;
        p.x = pk2(a0.x, a0.y); p.y = pk2(a0.z, a0.w);
        p.z = pk2(a1.x, a1.y); p.w = pk2(a1.z, a1.w);
        *(uint4*)((char*)Xl + ((row * 256 + ke * 2) ^ ((row & 7) << 4))) = p;
    }
    __syncthreads();

    const int lane  = tid & 63;
    const int wv    = tid >> 6;
    const int l15   = lane & 15;
    const int lk    = lane >> 4;
    const int strip = wv * 16;
    const int xrow_l = strip + l15;

    f32x4 qa[2], ka[2];
    #pragma unroll
    for (int h = 0; h < 2; ++h) {
        qa[h] = (f32x4){0.f, 0.f, 0.f, 0.f};
        ka[h] = (f32x4){0.f, 0.f, 0.f, 0.f};
    }

    #pragma unroll
    for (int kt = 0; kt < 4; ++kt) {
        bf16x8 x = *(const bf16x8*)((const char*)Xl +
            ((xrow_l * 256 + kt * 64 + lk * 16) ^ ((xrow_l & 7) << 4)));
        #pragma unroll
        for (int h = 0; h < 2; ++h) {
            bf16x8 wq = *(const bf16x8*)&Wqt[(h * 16 + l15) * 128 + kt * 32 + lk * 8];
            bf16x8 wk = *(const bf16x8*)&Wkt[(h * 16 + l15) * 128 + kt * 32 + lk * 8];
            qa[h] = mfma16(wq, x, qa[h]);
            ka[h] = mfma16(wk, x, ka[h]);
        }
    }

    const int xrow = row0 + strip + l15;
    const int n = xrow / S;
    const int l = xrow % S + LOFF;
    const size_t base = (size_t)n * 480 + (size_t)l * 32;
    #pragma unroll
    for (int h = 0; h < 2; ++h) {
        int rb = h * 16 + lk * 4;
        ushort4 pq, pk_;
        pq.x = f2bf(qa[h][0]); pq.y = f2bf(qa[h][1]);
        pq.z = f2bf(qa[h][2]); pq.w = f2bf(qa[h][3]);
        pk_.x = f2bf(ka[h][0]); pk_.y = f2bf(ka[h][1]);
        pk_.z = f2bf(ka[h][2]); pk_.w = f2bf(ka[h][3]);
        *(ushort4*)&eq[base + rb] = pq;
        *(ushort4*)&ek[base + rb] = pk_;
    }
}

__global__ __launch_bounds__(256) void proj_kernel(
    const float* __restrict__ X0, const float* __restrict__ X1,
    const float* __restrict__ X2,
    const unsigned short* __restrict__ Wqt,
    const unsigned short* __restrict__ Wk0t,
    const unsigned short* __restrict__ Wk1t,
    const unsigned short* __restrict__ Wk2t,
    unsigned short* __restrict__ eq, unsigned short* __restrict__ ek)
{
    __shared__ __align__(16) unsigned short Xl[64 * 128];
    const int b = blockIdx.x;
    if (b < 384)
        proj_body<3, 0>(X0, Wqt, Wk0t, eq, ek, b * 64, Xl);
    else if (b < 1024)
        proj_body<5, 3>(X1, Wqt, Wk1t, eq, ek, (b - 384) * 64, Xl);
    else
        proj_body<7, 8>(X2, Wqt, Wk2t, eq, ek, (b - 1024) * 64, Xl);
}

// ---------------------------------------------------------------------------
// Kernel 2: wn = LayerNorm(sum_l rej(q) . rej(k)) — gather-heavy, no LDS,
// high occupancy to hide random-access latency. Half-wave (32 r-lanes) / edge.
// ---------------------------------------------------------------------------
__global__ __launch_bounds__(256) void wn_kernel(
    const unsigned short* __restrict__ eq, const unsigned short* __restrict__ ek,
    const float* __restrict__ r0, const float* __restrict__ r1,
    const float* __restrict__ r2, const int* __restrict__ eidx,
    const float* __restrict__ ln_g, const float* __restrict__ ln_b,
    unsigned short* __restrict__ wn)
{
    const int tid = threadIdx.x;
    const int r   = tid & 31;
    const int e   = blockIdx.x * 8 + (tid >> 5);
    const float g  = ln_g[r];
    const float bb = ln_b[r];
    const int nj = eidx[e];
    const int ni = eidx[N_EDGES + e];

    float q[15], k[15], rv[15];
    const unsigned short* qp = eq + (size_t)ni * 480 + r;
    const unsigned short* kp = ek + (size_t)nj * 480 + r;
    #pragma unroll
    for (int l = 0; l < 15; ++l) { q[l] = bf2f(qp[l * 32]); k[l] = bf2f(kp[l * 32]); }
    #pragma unroll
    for (int c = 0; c < 3; ++c) rv[c]     = r0[e * 3 + c];
    #pragma unroll
    for (int c = 0; c < 5; ++c) rv[3 + c] = r1[e * 5 + c];
    #pragma unroll
    for (int c = 0; c < 7; ++c) rv[8 + c] = r2[e * 7 + c];

    float dq, dk;
    dq = q[0]*rv[0] + q[1]*rv[1] + q[2]*rv[2];
    dk = k[0]*rv[0] + k[1]*rv[1] + k[2]*rv[2];
    #pragma unroll
    for (int l = 0; l < 3; ++l) { q[l] -= dq * rv[l]; k[l] -= dk * rv[l]; }
    dq = 0.f; dk = 0.f;
    #pragma unroll
    for (int l = 3; l < 8; ++l) { dq += q[l]*rv[l]; dk += k[l]*rv[l]; }
    #pragma unroll
    for (int l = 3; l < 8; ++l) { q[l] -= dq * rv[l]; k[l] -= dk * rv[l]; }
    dq = 0.f; dk = 0.f;
    #pragma unroll
    for (int l = 8; l < 15; ++l) { dq += q[l]*rv[l]; dk += k[l]*rv[l]; }
    #pragma unroll
    for (int l = 8; l < 15; ++l) { q[l] -= dq * rv[l]; k[l] -= dk * rv[l]; }

    float w = 0.f;
    #pragma unroll
    for (int l = 0; l < 15; ++l) w = fmaf(q[l], k[l], w);

    float s = w, s2 = w * w;
    s += __shfl_xor(s, 1);  s2 += __shfl_xor(s2, 1);
    s += __shfl_xor(s, 2);  s2 += __shfl_xor(s2, 2);
    s += __shfl_xor(s, 4);  s2 += __shfl_xor(s2, 4);
    s += __shfl_xor(s, 8);  s2 += __shfl_xor(s2, 8);
    s += __shfl_xor(s, 16); s2 += __shfl_xor(s2, 16);
    const float mu  = s * (1.f / 32.f);
    const float var = s2 * (1.f / 32.f) - mu * mu;
    const float wnv = (w - mu) * rsqrtf(var + LN_EPS) * g + bb;
    wn[(size_t)e * 32 + r] = f2bf(wnv);
}

// ---------------------------------------------------------------------------
// Kernel 3: streaming MFMA GEMMs + epilogue. 64 edges/block, 4 waves,
// wave w owns output cols [w*32, w*32+32).
// ---------------------------------------------------------------------------
__global__ __launch_bounds__(256) void edge_kernel(
    const float* __restrict__ t_ij,
    const unsigned short* __restrict__ wn,
    const unsigned short* __restrict__ Wtw, const float* __restrict__ b_w,
    const unsigned short* __restrict__ Wt1, const float* __restrict__ b_t1,
    const unsigned short* __restrict__ Wt2, const float* __restrict__ b_t2,
    float* __restrict__ out)
{
    __shared__ __align__(16) unsigned short At[64 * 128];  // t_ij tile
    __shared__ __align__(16) unsigned short Ht[64 * 128];  // h tile

    const int tid  = threadIdx.x;
    const int tile = blockIdx.x * 64;

    // ---- stage t_ij tile -> bf16 swizzled At ----
    #pragma unroll
    for (int i = 0; i < 4; ++i) {
        int c   = tid + i * 256;
        int row = c >> 4;
        int ke  = (c & 15) * 8;
        const float* src = &t_ij[(size_t)(tile + row) * 128 + ke];
        float4 a0 = *(const float4*)src;
        float4 a1 = *(const float4*)(src + 4);
        uint4 p;
        p.x = pk2(a0.x, a0.y); p.y = pk2(a0.z, a0.w);
        p.z = pk2(a1.x, a1.y); p.w = pk2(a1.z, a1.w);
        *(uint4*)((char*)At + ((row * 256 + ke * 2) ^ ((row & 7) << 4))) = p;
    }

    const int lane = tid & 63;
    const int wv   = tid >> 6;
    const int wc   = wv * 32;
    const int l15  = lane & 15;
    const int lk   = lane >> 4;

    // ---- dw GEMM: dw = wn @ W_w  (wn read directly from global, K=32) ----
    bf16x8 wwf[2];
    #pragma unroll
    for (int ct = 0; ct < 2; ++ct)
        wwf[ct] = *(const bf16x8*)&Wtw[(wc + ct * 16 + l15) * 32 + lk * 8];

    f32x4 dac[4][2];
    #pragma unroll
    for (int rt = 0; rt < 4; ++rt) {
        bf16x8 a = *(const bf16x8*)&wn[(size_t)(tile + rt * 16 + l15) * 32 + lk * 8];
        dac[rt][0] = mfma16(a, wwf[0], (f32x4){0.f, 0.f, 0.f, 0.f});
        dac[rt][1] = mfma16(a, wwf[1], (f32x4){0.f, 0.f, 0.f, 0.f});
    }

    __syncthreads();

    // ---- GEMM1: h = silu(t_ij @ W_t1 + b_t1) ----
    bf16x8 w1f[4][2];
    #pragma unroll
    for (int kt = 0; kt < 4; ++kt)
        #pragma unroll
        for (int ct = 0; ct < 2; ++ct)
            w1f[kt][ct] = *(const bf16x8*)
                &Wt1[(size_t)(wc + ct * 16 + l15) * 128 + kt * 32 + lk * 8];

    f32x4 tac[4][2];
    #pragma unroll
    for (int rt = 0; rt < 4; ++rt)
        #pragma unroll
        for (int ct = 0; ct < 2; ++ct)
            tac[rt][ct] = (f32x4){0.f, 0.f, 0.f, 0.f};

    #pragma unroll
    for (int kt = 0; kt < 4; ++kt) {
        #pragma unroll
        for (int rt = 0; rt < 4; ++rt) {
            int row = rt * 16 + l15;
            bf16x8 a = *(const bf16x8*)((const char*)At +
                ((row * 256 + kt * 64 + lk * 16) ^ ((row & 7) << 4)));
            tac[rt][0] = mfma16(a, w1f[kt][0], tac[rt][0]);
            tac[rt][1] = mfma16(a, w1f[kt][1], tac[rt][1]);
        }
    }

    {
        float bt1v0 = b_t1[wc + l15];
        float bt1v1 = b_t1[wc + 16 + l15];
        #pragma unroll
        for (int rt = 0; rt < 4; ++rt)
            #pragma unroll
            for (int ct = 0; ct < 2; ++ct) {
                float bb  = ct ? bt1v1 : bt1v0;
                int   col = wc + ct * 16 + l15;
                #pragma unroll
                for (int r = 0; r < 4; ++r) {
                    int row = rt * 16 + lk * 4 + r;
                    float hv = silu_f(tac[rt][ct][r] + bb);
                    *(unsigned short*)((char*)Ht +
                        ((row * 256 + col * 2) ^ ((row & 7) << 4))) = f2bf(hv);
                }
            }
    }
    __syncthreads();

    // ---- GEMM2: t = h @ W_t2 ----
    bf16x8 w2f[4][2];
    #pragma unroll
    for (int kt = 0; kt < 4; ++kt)
        #pragma unroll
        for (int ct = 0; ct < 2; ++ct)
            w2f[kt][ct] = *(const bf16x8*)
                &Wt2[(size_t)(wc + ct * 16 + l15) * 128 + kt * 32 + lk * 8];

    f32x4 oac[4][2];
    #pragma unroll
    for (int rt = 0; rt < 4; ++rt)
        #pragma unroll
        for (int ct = 0; ct < 2; ++ct)
            oac[rt][ct] = (f32x4){0.f, 0.f, 0.f, 0.f};

    #pragma unroll
    for (int kt = 0; kt < 4; ++kt) {
        #pragma unroll
        for (int rt = 0; rt < 4; ++rt) {
            int row = rt * 16 + l15;
            bf16x8 a = *(const bf16x8*)((const char*)Ht +
                ((row * 256 + kt * 64 + lk * 16) ^ ((row & 7) << 4)));
            oac[rt][0] = mfma16(a, w2f[kt][0], oac[rt][0]);
            oac[rt][1] = mfma16(a, w2f[kt][1], oac[rt][1]);
        }
    }

    // ---- Epilogue: out = (dw + b_w) * silu(t + b_t2) ----
    {
        float bw0 = b_w[wc + l15],  bw1 = b_w[wc + 16 + l15];
        float b20 = b_t2[wc + l15], b21 = b_t2[wc + 16 + l15];
        #pragma unroll
        for (int rt = 0; rt < 4; ++rt)
            #pragma unroll
            for (int ct = 0; ct < 2; ++ct) {
                float bwv = ct ? bw1 : bw0;
                float b2v = ct ? b21 : b20;
                int   col = wc + ct * 16 + l15;
                #pragma unroll
                for (int r = 0; r < 4; ++r) {
                    int row = rt * 16 + lk * 4 + r;
                    float dwv = dac[rt][ct][r] + bwv;
                    float tv  = silu_f(oac[rt][ct][r] + b2v);
                    out[(size_t)(tile + row) * 128 + col] = dwv * tv;
                }
            }
    }
}

extern "C" void kernel_launch(void* const* d_in, const int* in_sizes, int n_in,
                              void* d_out, int out_size, void* d_ws, size_t ws_size,
                              hipStream_t stream) {
    (void)in_sizes; (void)n_in; (void)out_size; (void)ws_size;
    const float* X0   = (const float*)d_in[0];
    const float* X1   = (const float*)d_in[1];
    const float* X2   = (const float*)d_in[2];
    const float* t_ij = (const float*)d_in[3];
    const float* r0   = (const float*)d_in[4];
    const float* r1   = (const float*)d_in[5];
    const float* r2   = (const float*)d_in[6];
    const int*   eidx = (const int*)d_in[7];
    const float* Wvq  = (const float*)d_in[8];
    const float* Wvk0 = (const float*)d_in[9];
    const float* Wvk1 = (const float*)d_in[10];
    const float* Wvk2 = (const float*)d_in[11];
    const float* ln_g = (const float*)d_in[12];
    const float* ln_b = (const float*)d_in[13];
    const float* W_w  = (const float*)d_in[14];
    const float* b_w  = (const float*)d_in[15];
    const float* W_t1 = (const float*)d_in[16];
    const float* b_t1 = (const float*)d_in[17];
    const float* W_t2 = (const float*)d_in[18];
    const float* b_t2 = (const float*)d_in[19];
    float* out = (float*)d_out;

    unsigned short* eq   = (unsigned short*)d_ws;          // [N,15,32] bf16
    unsigned short* ek   = eq  + (size_t)N_NODES * 480;
    unsigned short* wn   = ek  + (size_t)N_NODES * 480;    // [E,32] bf16
    unsigned short* Wtw  = wn  + (size_t)N_EDGES * 32;
    unsigned short* Wt1b = Wtw  + 4096;
    unsigned short* Wt2b = Wt1b + 16384;
    unsigned short* Wqt  = Wt2b + 16384;
    unsigned short* Wk0t = Wqt  + 4096;
    unsigned short* Wk1t = Wk0t + 4096;
    unsigned short* Wk2t = Wk1t + 4096;

    prep_kernel<<<64, 256, 0, stream>>>(W_w, W_t1, W_t2, Wvq, Wvk0, Wvk1, Wvk2,
                                        Wtw, Wt1b, Wt2b, Wqt, Wk0t, Wk1t, Wk2t);
    proj_kernel<<<1920, 256, 0, stream>>>(X0, X1, X2, Wqt, Wk0t, Wk1t, Wk2t,
                                          eq, ek);
    wn_kernel<<<N_EDGES / 8, 256, 0, stream>>>(eq, ek, r0, r1, r2, eidx,
                                               ln_g, ln_b, wn);
    edge_kernel<<<N_EDGES / 64, 256, 0, stream>>>(t_ij, wn, Wtw, b_w,
                                                  Wt1b, b_t1, Wt2b, b_t2, out);
}